// Round 7
// baseline (394.875 us; speedup 1.0000x reference)
//
#include <hip/hip_runtime.h>

// B=8, L=2048, C=256, D=32. Four attentions (ecg/pcg intra/inter),
// out = concat(inter + scalar*intra) -> (8,2048,512) f32.
//
// Pipeline:
//   1) hipMemsetAsync(d_out, 0); all four attentions atomically accumulate.
//   2) deint_kernel : x f32 interleaved -> xe, xp bf16 [16384][256]
//   3) wcat_kernel  : 12 f32 weights -> bf16 B^T WT[1280][256] (Q rows pre-scaled
//      by log2e/sqrt(32)); row group g*64 matches proj job g's 64 outputs.
//   4) proj_kernel  : xe/xp @ WT -> Q[4],K[4],V^T[4]. 128x64 tiles; B staged once
//      (vectorized); A explicit reg->LDS double-buffer (BK=64).
//   5) flash_kernel : 512 blocks x 256 thr, 4 waves share V tile. EXPLICIT reg
//      double-buffer staging (no global_load_lds: avoids compiler's conservative
//      vmcnt(0) DMA-vs-ds_read drain that serialized round 6). S^T trick + lane-pair
//      shfl P transform; fixed-max exp2 softmax; ones-MFMA row sums; atomic epilogue.

typedef __bf16 v8bf __attribute__((ext_vector_type(8)));
typedef float  v16f __attribute__((ext_vector_type(16)));
typedef unsigned int u32;

#define QSCALE 0.25500526817276613f  // log2(e)/sqrt(32)

union frag_u { u32 d[4]; v8bf v; };
union pk_u { unsigned short s[2]; u32 d; };

static __device__ inline u32 pack_bf16(float x, float y) {
  pk_u u;
  __bf16 a = (__bf16)x, b = (__bf16)y;
  u.s[0] = *(unsigned short*)&a;
  u.s[1] = *(unsigned short*)&b;
  return u.d;
}

// ---------------------------------------------------------------- deinterleave
__global__ __launch_bounds__(256) void deint_kernel(const float* __restrict__ x,
                                                    __bf16* __restrict__ xe,
                                                    __bf16* __restrict__ xp) {
  const size_t i = (size_t)blockIdx.x * 256 + threadIdx.x;
  const float4* xin = (const float4*)(x + i * 16);
  float4 a = xin[0], b = xin[1], c = xin[2], d = xin[3];
  v8bf ev, pv;
  ev[0]=(__bf16)a.x; ev[1]=(__bf16)a.z; ev[2]=(__bf16)b.x; ev[3]=(__bf16)b.z;
  ev[4]=(__bf16)c.x; ev[5]=(__bf16)c.z; ev[6]=(__bf16)d.x; ev[7]=(__bf16)d.z;
  pv[0]=(__bf16)a.y; pv[1]=(__bf16)a.w; pv[2]=(__bf16)b.y; pv[3]=(__bf16)b.w;
  pv[4]=(__bf16)c.y; pv[5]=(__bf16)c.w; pv[6]=(__bf16)d.y; pv[7]=(__bf16)d.w;
  *(v8bf*)(xe + i * 8) = ev;
  *(v8bf*)(xp + i * 8) = pv;
}

// ---------------------------------------------------------------- weight pack
struct WcatArgs {
  const float* src[40];   // per 32-row span
  int c0[40];
  int dout[40];
  float scale[40];
  __bf16* wt;             // [1280][256]
};

// grid 1280 blocks (one WT row each), 256 thr (k). WT[r][k] = src[k][c0 + r%32] * scale.
__global__ __launch_bounds__(256) void wcat_kernel(WcatArgs wa) {
  const int r = blockIdx.x, e = r >> 5, k = threadIdx.x;
  const float v = wa.src[e][(size_t)k * wa.dout[e] + wa.c0[e] + (r & 31)] * wa.scale[e];
  wa.wt[(size_t)r * 256 + k] = (__bf16)v;
}

// ---------------------------------------------------------------- projections
struct ProjArgs {
  const __bf16* xe;
  const __bf16* xp;
  const __bf16* wt;
  __bf16* q[4];
  __bf16* k[4];
  __bf16* vt[4];
};

// grid (20 jobs, 128 row-tiles of 128), block 256 (4 waves x 32 rows, 64 cols).
__global__ __launch_bounds__(256) void proj_kernel(ProjArgs pa) {
  const int job = blockIdx.x;
  const int rb  = blockIdx.y * 128;
  const int tid = threadIdx.x;
  const int lane = tid & 63, w = tid >> 6;
  const int l31 = lane & 31, lh = lane >> 5;

  __shared__ __bf16 lds_B[64 * 264];     // rows 528B (132 words, stagger 4) 
  __shared__ __bf16 lds_A[2][128 * 72];  // dbuf BK=64, rows 144B (36 words, stagger 4)

  int src, vcol0 = 0, vmode = 0;
  __bf16* dqk[2] = {nullptr, nullptr};
  __bf16* vdst = nullptr;
  if (job < 4) {
    switch (job) {
      case 0: src=0; dqk[0]=pa.q[0]; dqk[1]=pa.q[1]; break;
      case 1: src=0; dqk[0]=pa.k[0]; dqk[1]=pa.k[3]; break;
      case 2: src=1; dqk[0]=pa.q[2]; dqk[1]=pa.q[3]; break;
      default:src=1; dqk[0]=pa.k[1]; dqk[1]=pa.k[2]; break;
    }
  } else {
    const int vi = (job - 4) >> 2, t = (job - 4) & 3;
    const int vbuf = (vi==0) ? 0 : (vi==1) ? 3 : (vi==2) ? 1 : 2;
    vmode = 1; src = vi >> 1;
    vcol0 = t*64; vdst = pa.vt[vbuf];
  }

  const __bf16* X = src ? pa.xp : pa.xe;

  // B loads (once): WT rows job*64..+63, each 512B
  int4 breg[8];
  int brow[8], bch[8];
#pragma unroll
  for (int i = 0; i < 8; ++i) {
    const int idx = tid + i*256;
    brow[i] = idx >> 5; bch[i] = idx & 31;
    breg[i] = *(const int4*)(pa.wt + ((size_t)(job*64 + brow[i])*256 + bch[i]*8));
  }
  // A slice loads
  int arow[4], ach[4];
#pragma unroll
  for (int i = 0; i < 4; ++i) {
    const int idx = tid + i*256;
    arow[i] = idx >> 3; ach[i] = idx & 7;
  }
  int4 areg[4];
#define LOAD_A(kb)                                                              \
  _Pragma("unroll")                                                             \
  for (int i = 0; i < 4; ++i)                                                   \
    areg[i] = *(const int4*)(X + ((size_t)(rb + arow[i])*256 + (kb)*64 + ach[i]*8));

#define WRITE_A(buf)                                                            \
  _Pragma("unroll")                                                             \
  for (int i = 0; i < 4; ++i)                                                   \
    *(int4*)&lds_A[buf][arow[i]*72 + ach[i]*8] = areg[i];

  LOAD_A(0)
#pragma unroll
  for (int i = 0; i < 8; ++i)
    *(int4*)&lds_B[brow[i]*264 + bch[i]*8] = breg[i];
  WRITE_A(0)
  LOAD_A(1)
  __syncthreads();

  v16f acc[2];
#pragma unroll
  for (int n = 0; n < 2; ++n)
#pragma unroll
    for (int i = 0; i < 16; ++i) acc[n][i] = 0.f;

  for (int kb = 0; kb < 4; ++kb) {
    if (kb < 3) WRITE_A((kb + 1) & 1)
    if (kb < 2) LOAD_A(kb + 2)
    const __bf16* ab = &lds_A[kb & 1][0];
#pragma unroll
    for (int kk = 0; kk < 4; ++kk) {
      const v8bf af = *(const v8bf*)&ab[(w*32 + l31)*72 + (kk*2 + lh)*8];
#pragma unroll
      for (int nt = 0; nt < 2; ++nt) {
        const v8bf bf = *(const v8bf*)&lds_B[(nt*32 + l31)*264 + kb*64 + kk*16 + lh*8];
        acc[nt] = __builtin_amdgcn_mfma_f32_32x32x16_bf16(af, bf, acc[nt], 0, 0, 0);
      }
    }
    __syncthreads();
  }

  if (!vmode) {
    // Q/K row-major [16384][32] (scale pre-folded into WT)
#pragma unroll
    for (int nt = 0; nt < 2; ++nt) {
      __bf16* dst = dqk[nt];
#pragma unroll
      for (int r = 0; r < 16; ++r) {
        const int row = rb + w*32 + (r & 3) + 8*(r >> 2) + 4*lh;
        dst[(size_t)row*32 + l31] = (__bf16)acc[nt][r];
      }
    }
  } else {
    // V: transpose 128x64 tile through LDS (reuse lds_A), write V^T coalesced
    __bf16 (*lds_t)[136] = (__bf16 (*)[136])&lds_A[0][0];  // 64 x 272B rows
#pragma unroll
    for (int nt = 0; nt < 2; ++nt) {
#pragma unroll
      for (int r = 0; r < 16; ++r) {
        const int row = w*32 + (r & 3) + 8*(r >> 2) + 4*lh;
        lds_t[nt*32 + l31][row] = (__bf16)acc[nt][r];
      }
    }
    __syncthreads();
    const int bb = rb >> 11, ll0 = rb & 2047;
    for (int i = tid; i < 1024; i += 256) {
      const int vrow = i >> 4, seg = i & 15;
      *(int4*)&vdst[((size_t)(bb*256 + vcol0 + vrow))*2048 + ll0 + seg*8] =
          *(const int4*)&lds_t[vrow][seg*8];
    }
  }
}

// ---------------------------------------------------------------- flash attention
struct FlashArgs {
  const __bf16* q[4];
  const __bf16* k[4];
  const __bf16* v[4];
  const float* alpha;
  const float* gamma;
  float* out;
};

// 512 blocks x 256 thr. flat = pair + 32*qt (pair%8 pins (att,bb) to an XCD).
// Wave: 32 q x 256 vcols, 32 kt of 64 keys. V staged global->VGPR->LDS (explicit
// dbuf; plain loads don't alias LDS so no conservative vmcnt drain). K prefetched.
__global__ __launch_bounds__(256, 2) void flash_kernel(FlashArgs fa) {
  const int flat = blockIdx.x;
  const int pair = flat & 31, qt = flat >> 5;
  const int att = pair & 3, bb = pair >> 2;
  const int tid = threadIdx.x;
  const int lane = tid & 63, w = tid >> 6;
  const int l31 = lane & 31, lh = lane >> 5;
  const int l7 = lane & 7, l8 = lane >> 3;

  __shared__ __bf16 v_lds[2][16384];  // 2 x (256 vcols x 64 keys); 128B rows, XOR-swizzled

  const __bf16* Q  = fa.q[att] + (size_t)bb*2048*32;
  const __bf16* Kb = fa.k[att] + (size_t)bb*2048*32;
  const __bf16* Vb = fa.v[att] + (size_t)bb*256*2048;
  float scv = 1.0f;
  if (att == 0) scv = fa.alpha[0];
  if (att == 2) scv = fa.gamma[0];
  const int zcol = (att >> 1) * 256;

  // Q B-frags (resident): B[n=q=l31][k=d = c*16 + lh*8 + j]
  const int qrow = qt*128 + w*32 + l31;
  const v8bf qf0 = *(const v8bf*)&Q[(size_t)qrow*32 + lh*8];
  const v8bf qf1 = *(const v8bf*)&Q[(size_t)qrow*32 + 16 + lh*8];

  // V staging: wave w owns vcol rows w*64..+63; global chunk xor-swizzled (l7^l8)
  const char* vgbase = (const char*)Vb + (size_t)(w*64 + l8)*4096 + (size_t)(l7 ^ l8)*16;

  int4 vreg[8];
#define LOAD_V(kt)                                                              \
  {                                                                             \
    const char* g = vgbase + (size_t)(kt)*128;                                  \
    _Pragma("unroll")                                                           \
    for (int i = 0; i < 8; ++i)                                                 \
      vreg[i] = *(const int4*)(g + (size_t)i*32768);                            \
  }
#define WRITE_V(buf)                                                            \
  _Pragma("unroll")                                                             \
  for (int i = 0; i < 8; ++i)                                                   \
    *(int4*)&v_lds[buf][(w*64 + i*8)*64 + lane*8] = vreg[i];

  int voff[4];
#pragma unroll
  for (int kc = 0; kc < 4; ++kc)
    voff[kc] = ((kc*2 + lh) ^ l7) * 8;

  v8bf ones;
#pragma unroll
  for (int i = 0; i < 8; ++i) ones[i] = (__bf16)1.0f;

  v16f acc[8], den;
#pragma unroll
  for (int n = 0; n < 8; ++n)
#pragma unroll
    for (int i = 0; i < 16; ++i) acc[n][i] = 0.f;
#pragma unroll
  for (int i = 0; i < 16; ++i) den[i] = 0.f;

  // K A-frag prefetch: A[m=key = t*32+l31][k=d]
  v8bf kfr[2][2];
#define LOAD_K(kb)                                                              \
  _Pragma("unroll")                                                             \
  for (int t = 0; t < 2; ++t)                                                   \
    _Pragma("unroll")                                                           \
    for (int c = 0; c < 2; ++c)                                                 \
      kfr[t][c] = *(const v8bf*)&Kb[((size_t)((kb) + t*32 + l31))*32 + c*16 + lh*8];

  // prologue: tile0 -> LDS buf0; tile1 held in regs; kf(0) in regs
  LOAD_V(0)
  WRITE_V(0)
  LOAD_V(1)
  LOAD_K(0)
  __syncthreads();

  for (int kt = 0; kt < 32; ++kt) {
    const int cur = kt & 1;

    // stage tile kt+1 (regs, loaded last iter) into the other buffer
    if (kt < 31) WRITE_V(cur ^ 1)
    // issue loads for tile kt+2
    if (kt < 30) LOAD_V(kt + 2)

    // S^T = K.Q^T (log2 domain): C[row=key][col=q]
    v16f st0, st1;
#pragma unroll
    for (int i = 0; i < 16; ++i) { st0[i] = 0.f; st1[i] = 0.f; }
    st0 = __builtin_amdgcn_mfma_f32_32x32x16_bf16(kfr[0][0], qf0, st0, 0, 0, 0);
    st0 = __builtin_amdgcn_mfma_f32_32x32x16_bf16(kfr[0][1], qf1, st0, 0, 0, 0);
    st1 = __builtin_amdgcn_mfma_f32_32x32x16_bf16(kfr[1][0], qf0, st1, 0, 0, 0);
    st1 = __builtin_amdgcn_mfma_f32_32x32x16_bf16(kfr[1][1], qf1, st1, 0, 0, 0);

    // prefetch next K frags (fly during exp2/PV)
    if (kt < 31) LOAD_K((kt + 1) * 64)

    // P = exp2(S^T), bf16-packed key-pair dwords (fixed-max: scores are small)
    u32 pk0[8], pk1[8];
#pragma unroll
    for (int i = 0; i < 8; ++i) {
      pk0[i] = pack_bf16(__builtin_exp2f(st0[2*i]), __builtin_exp2f(st0[2*i + 1]));
      pk1[i] = pack_bf16(__builtin_exp2f(st1[2*i]), __builtin_exp2f(st1[2*i + 1]));
    }

    // P A-frags via lane-pair exchange: keep own key-quad, send the other.
    v8bf pf[4];
#pragma unroll
    for (int half = 0; half < 2; ++half) {
      const u32* pk = half ? pk1 : pk0;
#pragma unroll
      for (int f2 = 0; f2 < 2; ++f2) {
        const u32 keep0 = lh ? pk[f2*4 + 2] : pk[f2*4 + 0];
        const u32 keep1 = lh ? pk[f2*4 + 3] : pk[f2*4 + 1];
        const u32 send0 = lh ? pk[f2*4 + 0] : pk[f2*4 + 2];
        const u32 send1 = lh ? pk[f2*4 + 1] : pk[f2*4 + 3];
        const u32 recv0 = (u32)__shfl_xor((int)send0, 32, 64);
        const u32 recv1 = (u32)__shfl_xor((int)send1, 32, 64);
        frag_u fu;
        fu.d[0] = lh ? recv0 : keep0;
        fu.d[1] = lh ? recv1 : keep1;
        fu.d[2] = lh ? keep0 : recv0;
        fu.d[3] = lh ? keep1 : recv1;
        pf[half*2 + f2] = fu.v;
      }
    }

    // PV += P @ V^T ; row sums via ones B-frag
    const __bf16* vb = &v_lds[cur][0];
#pragma unroll
    for (int kc = 0; kc < 4; ++kc) {
      den = __builtin_amdgcn_mfma_f32_32x32x16_bf16(pf[kc], ones, den, 0, 0, 0);
#pragma unroll
      for (int nt = 0; nt < 8; ++nt) {
        const v8bf vf = *(const v8bf*)&vb[(nt*32 + l31)*64 + voff[kc]];
        acc[nt] = __builtin_amdgcn_mfma_f32_32x32x16_bf16(pf[kc], vf, acc[nt], 0, 0, 0);
      }
    }
    __syncthreads();
  }

  // epilogue: atomic accumulate scv * acc / den
  float* outp = fa.out + (size_t)(bb*2048 + qt*128 + w*32) * 512 + zcol;
#pragma unroll
  for (int r = 0; r < 16; ++r) {
    const int row = (r & 3) + 8*(r >> 2) + 4*lh;
    const float f = scv / den[r];
#pragma unroll
    for (int nt = 0; nt < 8; ++nt)
      unsafeAtomicAdd(&outp[(size_t)row*512 + nt*32 + l31], acc[nt][r] * f);
  }
}

// ---------------------------------------------------------------- launch
extern "C" void kernel_launch(void* const* d_in, const int* in_sizes, int n_in,
                              void* d_out, int out_size, void* d_ws, size_t ws_size,
                              hipStream_t stream) {
  (void)in_sizes; (void)n_in; (void)out_size; (void)ws_size;

  __bf16* wsp = (__bf16*)d_ws;
  const size_t XE = (size_t)16384 * 256;
  const size_t QK = (size_t)16384 * 32;
  const size_t VT = (size_t)8 * 256 * 2048;

  __bf16* xe = wsp;
  __bf16* xp = wsp + XE;
  __bf16* base = wsp + 2*XE;

  ProjArgs pa;
  pa.xe = xe; pa.xp = xp;
  const float* x = (const float*)d_in[0];
  const float* wsrc[12];
  for (int i = 0; i < 12; ++i) wsrc[i] = (const float*)d_in[1 + i];
  for (int i = 0; i < 4; ++i) pa.q[i]  = base + (size_t)i * QK;
  for (int i = 0; i < 4; ++i) pa.k[i]  = base + (size_t)(4 + i) * QK;
  for (int i = 0; i < 4; ++i) pa.vt[i] = base + 8*QK + (size_t)i * VT;
  __bf16* wt = base + 8*QK + 4*VT;
  pa.wt = wt;

  // wcat table: 40 x 32-row spans matching proj jobs (2 spans per job half... 2 per job)
  WcatArgs wa;
  wa.wt = wt;
  // QK jobs: job g half h
  const int qk_w[4][2] = {{0, 3}, {1, 10}, {6, 9}, {4, 7}};  // w1,w4 | w2,w11 | w7,w10 | w5,w8
  const float qk_s[4] = {QSCALE, 1.0f, QSCALE, 1.0f};
  for (int g = 0; g < 4; ++g)
    for (int h = 0; h < 2; ++h) {
      const int e = g*2 + h;
      wa.src[e] = wsrc[qk_w[g][h]];
      wa.c0[e] = 0; wa.dout[e] = 32; wa.scale[e] = qk_s[g];
    }
  const int v_w[4] = {2, 11, 5, 8};  // w3, w12, w6, w9
  for (int vi = 0; vi < 4; ++vi)
    for (int t = 0; t < 4; ++t)
      for (int h = 0; h < 2; ++h) {
        const int e = (4 + vi*4 + t)*2 + h;
        wa.src[e] = wsrc[v_w[vi]];
        wa.c0[e] = t*64 + h*32; wa.dout[e] = 256; wa.scale[e] = 1.0f;
      }

  hipMemsetAsync(d_out, 0, (size_t)8*2048*512*4, stream);
  hipLaunchKernelGGL(deint_kernel, dim3(2048), dim3(256), 0, stream, x, xe, xp);
  hipLaunchKernelGGL(wcat_kernel, dim3(1280), dim3(256), 0, stream, wa);
  hipLaunchKernelGGL(proj_kernel, dim3(20, 128), dim3(256), 0, stream, pa);

  FlashArgs fl;
  for (int i = 0; i < 4; ++i) { fl.q[i] = pa.q[i]; fl.k[i] = pa.k[i]; fl.v[i] = pa.vt[i]; }
  fl.alpha = (const float*)d_in[13];
  fl.gamma = (const float*)d_in[14];
  fl.out = (float*)d_out;
  hipLaunchKernelGGL(flash_kernel, dim3(512), dim3(256), 0, stream, fl);
}

// Round 8
// 293.718 us; speedup vs baseline: 1.3444x; 1.3444x over previous
//
#include <hip/hip_runtime.h>

// B=8, L=2048, C=256, D=32. Four attentions (ecg/pcg intra/inter),
// out = concat(inter + scalar*intra) -> (8,2048,512) f32.
//
// Pipeline:
//   1) hipMemsetAsync(d_out, 0); all four attentions atomically accumulate.
//   2) deint_kernel : x f32 interleaved -> xe, xp bf16 [16384][256]
//   3) wcat_kernel  : 12 f32 weights -> bf16 B^T WT[1280][256] (Q rows pre-scaled)
//   4) proj_kernel  : xe/xp @ WT -> Q[4],K[4], V in VF layout VF[b][k8][vcol][8keys]
//   5) flash_kernel : r6 structure (global_load_lds dbuf, S^T+shfl P transform,
//      fixed-max exp2 softmax, ones-MFMA row sums, atomic epilogue) with the V
//      tile in key-octet-major VF layout: PV ds_read_b128 is lane-contiguous
//      (conflict-free; r6 had structural 4-way conflicts = 8.4M cyc/dispatch),
//      and staging needs no XOR swizzle. Register budget identical to r6
//      (r7's reg-staging spilled: WRITE_SIZE 65->350MB).

typedef __bf16 v8bf __attribute__((ext_vector_type(8)));
typedef float  v16f __attribute__((ext_vector_type(16)));
typedef unsigned int u32;

typedef __attribute__((address_space(1))) const void gvoid;
typedef __attribute__((address_space(3))) void svoid;

#define QSCALE 0.25500526817276613f  // log2(e)/sqrt(32)

union frag_u { u32 d[4]; v8bf v; };
union pk_u { unsigned short s[2]; u32 d; };

static __device__ inline u32 pack_bf16(float x, float y) {
  pk_u u;
  __bf16 a = (__bf16)x, b = (__bf16)y;
  u.s[0] = *(unsigned short*)&a;
  u.s[1] = *(unsigned short*)&b;
  return u.d;
}

// ---------------------------------------------------------------- deinterleave
__global__ __launch_bounds__(256) void deint_kernel(const float* __restrict__ x,
                                                    __bf16* __restrict__ xe,
                                                    __bf16* __restrict__ xp) {
  const size_t i = (size_t)blockIdx.x * 256 + threadIdx.x;
  const float4* xin = (const float4*)(x + i * 16);
  float4 a = xin[0], b = xin[1], c = xin[2], d = xin[3];
  v8bf ev, pv;
  ev[0]=(__bf16)a.x; ev[1]=(__bf16)a.z; ev[2]=(__bf16)b.x; ev[3]=(__bf16)b.z;
  ev[4]=(__bf16)c.x; ev[5]=(__bf16)c.z; ev[6]=(__bf16)d.x; ev[7]=(__bf16)d.z;
  pv[0]=(__bf16)a.y; pv[1]=(__bf16)a.w; pv[2]=(__bf16)b.y; pv[3]=(__bf16)b.w;
  pv[4]=(__bf16)c.y; pv[5]=(__bf16)c.w; pv[6]=(__bf16)d.y; pv[7]=(__bf16)d.w;
  *(v8bf*)(xe + i * 8) = ev;
  *(v8bf*)(xp + i * 8) = pv;
}

// ---------------------------------------------------------------- weight pack
struct WcatArgs {
  const float* src[40];
  int c0[40];
  int dout[40];
  float scale[40];
  __bf16* wt;             // [1280][256]
};

__global__ __launch_bounds__(256) void wcat_kernel(WcatArgs wa) {
  const int r = blockIdx.x, e = r >> 5, k = threadIdx.x;
  const float v = wa.src[e][(size_t)k * wa.dout[e] + wa.c0[e] + (r & 31)] * wa.scale[e];
  wa.wt[(size_t)r * 256 + k] = (__bf16)v;
}

// ---------------------------------------------------------------- projections
struct ProjArgs {
  const __bf16* xe;
  const __bf16* xp;
  const __bf16* wt;
  __bf16* q[4];
  __bf16* k[4];
  __bf16* vt[4];   // VF layout: [b][k8][vcol][8 keys]
};

// grid (20 jobs, 128 row-tiles of 128), block 256 (4 waves x 32 rows, 64 cols).
__global__ __launch_bounds__(256) void proj_kernel(ProjArgs pa) {
  const int job = blockIdx.x;
  const int rb  = blockIdx.y * 128;
  const int tid = threadIdx.x;
  const int lane = tid & 63, w = tid >> 6;
  const int l31 = lane & 31, lh = lane >> 5;

  __shared__ __bf16 lds_B[64 * 264];     // rows 528B
  __shared__ __bf16 lds_A[2][128 * 72];  // dbuf BK=64, rows 144B

  int src, vcol0 = 0, vmode = 0;
  __bf16* dqk[2] = {nullptr, nullptr};
  __bf16* vdst = nullptr;
  if (job < 4) {
    switch (job) {
      case 0: src=0; dqk[0]=pa.q[0]; dqk[1]=pa.q[1]; break;
      case 1: src=0; dqk[0]=pa.k[0]; dqk[1]=pa.k[3]; break;
      case 2: src=1; dqk[0]=pa.q[2]; dqk[1]=pa.q[3]; break;
      default:src=1; dqk[0]=pa.k[1]; dqk[1]=pa.k[2]; break;
    }
  } else {
    const int vi = (job - 4) >> 2, t = (job - 4) & 3;
    const int vbuf = (vi==0) ? 0 : (vi==1) ? 3 : (vi==2) ? 1 : 2;
    vmode = 1; src = vi >> 1;
    vcol0 = t*64; vdst = pa.vt[vbuf];
  }

  const __bf16* X = src ? pa.xp : pa.xe;

  // B loads (once): WT rows job*64..+63
  int4 breg[8];
  int brow[8], bch[8];
#pragma unroll
  for (int i = 0; i < 8; ++i) {
    const int idx = tid + i*256;
    brow[i] = idx >> 5; bch[i] = idx & 31;
    breg[i] = *(const int4*)(pa.wt + ((size_t)(job*64 + brow[i])*256 + bch[i]*8));
  }
  int arow[4], ach[4];
#pragma unroll
  for (int i = 0; i < 4; ++i) {
    const int idx = tid + i*256;
    arow[i] = idx >> 3; ach[i] = idx & 7;
  }
  int4 areg[4];
#define LOAD_A(kb)                                                              \
  _Pragma("unroll")                                                             \
  for (int i = 0; i < 4; ++i)                                                   \
    areg[i] = *(const int4*)(X + ((size_t)(rb + arow[i])*256 + (kb)*64 + ach[i]*8));

#define WRITE_A(buf)                                                            \
  _Pragma("unroll")                                                             \
  for (int i = 0; i < 4; ++i)                                                   \
    *(int4*)&lds_A[buf][arow[i]*72 + ach[i]*8] = areg[i];

  LOAD_A(0)
#pragma unroll
  for (int i = 0; i < 8; ++i)
    *(int4*)&lds_B[brow[i]*264 + bch[i]*8] = breg[i];
  WRITE_A(0)
  LOAD_A(1)
  __syncthreads();

  v16f acc[2];
#pragma unroll
  for (int n = 0; n < 2; ++n)
#pragma unroll
    for (int i = 0; i < 16; ++i) acc[n][i] = 0.f;

  for (int kb = 0; kb < 4; ++kb) {
    if (kb < 3) WRITE_A((kb + 1) & 1)
    if (kb < 2) LOAD_A(kb + 2)
    const __bf16* ab = &lds_A[kb & 1][0];
#pragma unroll
    for (int kk = 0; kk < 4; ++kk) {
      const v8bf af = *(const v8bf*)&ab[(w*32 + l31)*72 + (kk*2 + lh)*8];
#pragma unroll
      for (int nt = 0; nt < 2; ++nt) {
        const v8bf bf = *(const v8bf*)&lds_B[(nt*32 + l31)*264 + kb*64 + kk*16 + lh*8];
        acc[nt] = __builtin_amdgcn_mfma_f32_32x32x16_bf16(af, bf, acc[nt], 0, 0, 0);
      }
    }
    __syncthreads();
  }

  if (!vmode) {
    // Q/K row-major [16384][32] (scale pre-folded into WT)
#pragma unroll
    for (int nt = 0; nt < 2; ++nt) {
      __bf16* dst = dqk[nt];
#pragma unroll
      for (int r = 0; r < 16; ++r) {
        const int row = rb + w*32 + (r & 3) + 8*(r >> 2) + 4*lh;
        dst[(size_t)row*32 + l31] = (__bf16)acc[nt][r];
      }
    }
  } else {
    // V: transpose 128keys x 64vcols tile through LDS, then write VF[b][k8][vcol]
    __bf16 (*lds_t)[136] = (__bf16 (*)[136])&lds_A[0][0];  // 64 x 272B rows
#pragma unroll
    for (int nt = 0; nt < 2; ++nt) {
#pragma unroll
      for (int r = 0; r < 16; ++r) {
        const int row = w*32 + (r & 3) + 8*(r >> 2) + 4*lh;
        lds_t[nt*32 + l31][row] = (__bf16)acc[nt][r];
      }
    }
    __syncthreads();
    const int bb = rb >> 11, k8base = (rb & 2047) >> 3;
    // i: seg = key-octet (0..15), vrow = vcol-in-tile (0..63): lanes contiguous in vcol
    for (int i = tid; i < 1024; i += 256) {
      const int seg = i >> 6, vrow = i & 63;
      *(int4*)&vdst[(((size_t)bb*256 + k8base + seg)*256 + vcol0 + vrow)*8] =
          *(const int4*)&lds_t[vrow][seg*8];
    }
  }
}

// ---------------------------------------------------------------- flash attention
struct FlashArgs {
  const __bf16* q[4];
  const __bf16* k[4];
  const __bf16* v[4];   // VF layout
  const float* alpha;
  const float* gamma;
  float* out;
};

// 512 blocks x 256 thr. flat = pair + 32*qt (pair%8 pins (att,bb) to an XCD).
// Wave: 32 q x 256 vcols, 32 kt of 64 keys. V tile dbuf-staged via global_load_lds
// in VF layout (no swizzle needed); PV reads are lane-contiguous -> conflict-free.
__global__ __launch_bounds__(256, 2) void flash_kernel(FlashArgs fa) {
  const int flat = blockIdx.x;
  const int pair = flat & 31, qt = flat >> 5;
  const int att = pair & 3, bb = pair >> 2;
  const int tid = threadIdx.x;
  const int lane = tid & 63, w = tid >> 6;
  const int l31 = lane & 31, lh = lane >> 5;

  __shared__ __bf16 v_lds[2][16384];  // 2 x (8 k8 x 256 vcols x 8 keys)

  const __bf16* Q  = fa.q[att] + (size_t)bb*2048*32;
  const __bf16* Kb = fa.k[att] + (size_t)bb*2048*32;
  const __bf16* VF = fa.v[att] + (size_t)bb*256*2048;  // VF[b][k8][vcol][8]
  float scv = 1.0f;
  if (att == 0) scv = fa.alpha[0];
  if (att == 2) scv = fa.gamma[0];
  const int zcol = (att >> 1) * 256;

  // Q B-frags (resident): B[n=q=l31][k=d = c*16 + lh*8 + j]
  const int qrow = qt*128 + w*32 + l31;
  const v8bf qf0 = *(const v8bf*)&Q[(size_t)qrow*32 + lh*8];
  const v8bf qf1 = *(const v8bf*)&Q[(size_t)qrow*32 + 16 + lh*8];

  // staging: 32 chunks of 1KB; wave w takes chunks w*8..w*8+7.
  // chunk c: k8local = c>>2, vcol-quarter = c&3. Global and LDS are both
  // contiguous in (vcol) so DMA is wave-uniform base + lane*16B.
#define STAGE_V(buf, kt)                                                        \
  {                                                                             \
    const size_t kb8 = (size_t)(kt) * 8;                                        \
    _Pragma("unroll")                                                           \
    for (int i = 0; i < 8; ++i) {                                               \
      const int c = w*8 + i, k8l = c >> 2, vq = c & 3;                          \
      __builtin_amdgcn_global_load_lds(                                         \
          (gvoid*)&VF[((kb8 + k8l)*256 + vq*64 + lane)*8],                      \
          (svoid*)&v_lds[buf][((size_t)(k8l*256 + vq*64 + lane))*8], 16, 0, 0); \
    }                                                                           \
  }

  v8bf ones;
#pragma unroll
  for (int i = 0; i < 8; ++i) ones[i] = (__bf16)1.0f;

  v16f acc[8], den;
#pragma unroll
  for (int n = 0; n < 8; ++n)
#pragma unroll
    for (int i = 0; i < 16; ++i) acc[n][i] = 0.f;
#pragma unroll
  for (int i = 0; i < 16; ++i) den[i] = 0.f;

  STAGE_V(0, 0)
  __syncthreads();

  for (int kt = 0; kt < 32; ++kt) {
    const int cur = kt & 1, kb = kt * 64;
    if (kt < 31) STAGE_V(cur ^ 1, kt + 1)

    // K A-frags: A[m=key = t*32+l31][k=d]
    v8bf kf[2][2];
#pragma unroll
    for (int t = 0; t < 2; ++t)
#pragma unroll
      for (int c = 0; c < 2; ++c)
        kf[t][c] = *(const v8bf*)&Kb[((size_t)(kb + t*32 + l31))*32 + c*16 + lh*8];

    // S^T = K.Q^T (log2 domain): C[row=key][col=q]
    v16f st0, st1;
#pragma unroll
    for (int i = 0; i < 16; ++i) { st0[i] = 0.f; st1[i] = 0.f; }
    st0 = __builtin_amdgcn_mfma_f32_32x32x16_bf16(kf[0][0], qf0, st0, 0, 0, 0);
    st0 = __builtin_amdgcn_mfma_f32_32x32x16_bf16(kf[0][1], qf1, st0, 0, 0, 0);
    st1 = __builtin_amdgcn_mfma_f32_32x32x16_bf16(kf[1][0], qf0, st1, 0, 0, 0);
    st1 = __builtin_amdgcn_mfma_f32_32x32x16_bf16(kf[1][1], qf1, st1, 0, 0, 0);

    // P = exp2(S^T), bf16-packed key-pair dwords (fixed-max: scores are small)
    u32 pk0[8], pk1[8];
#pragma unroll
    for (int i = 0; i < 8; ++i) {
      pk0[i] = pack_bf16(__builtin_exp2f(st0[2*i]), __builtin_exp2f(st0[2*i + 1]));
      pk1[i] = pack_bf16(__builtin_exp2f(st1[2*i]), __builtin_exp2f(st1[2*i + 1]));
    }

    // P A-frags via lane-pair exchange: keep own key-quad, send the other.
    v8bf pf[4];
#pragma unroll
    for (int half = 0; half < 2; ++half) {
      const u32* pk = half ? pk1 : pk0;
#pragma unroll
      for (int f2 = 0; f2 < 2; ++f2) {
        const u32 keep0 = lh ? pk[f2*4 + 2] : pk[f2*4 + 0];
        const u32 keep1 = lh ? pk[f2*4 + 3] : pk[f2*4 + 1];
        const u32 send0 = lh ? pk[f2*4 + 0] : pk[f2*4 + 2];
        const u32 send1 = lh ? pk[f2*4 + 1] : pk[f2*4 + 3];
        const u32 recv0 = (u32)__shfl_xor((int)send0, 32, 64);
        const u32 recv1 = (u32)__shfl_xor((int)send1, 32, 64);
        frag_u fu;
        fu.d[0] = lh ? recv0 : keep0;
        fu.d[1] = lh ? recv1 : keep1;
        fu.d[2] = lh ? keep0 : recv0;
        fu.d[3] = lh ? keep1 : recv1;
        pf[half*2 + f2] = fu.v;
      }
    }

    // PV += P @ V ; row sums via ones B-frag. VF read: lane-contiguous 16B.
    const __bf16* vb = &v_lds[cur][0];
#pragma unroll
    for (int kc = 0; kc < 4; ++kc) {
      den = __builtin_amdgcn_mfma_f32_32x32x16_bf16(pf[kc], ones, den, 0, 0, 0);
      const __bf16* vrow = &vb[(size_t)((kc*2 + lh)*256)*8];
#pragma unroll
      for (int nt = 0; nt < 8; ++nt) {
        const v8bf vf = *(const v8bf*)&vrow[(size_t)(nt*32 + l31)*8];
        acc[nt] = __builtin_amdgcn_mfma_f32_32x32x16_bf16(pf[kc], vf, acc[nt], 0, 0, 0);
      }
    }
    __syncthreads();  // drains staging vmcnt + all waves done with cur buffer
  }

  // epilogue: atomic accumulate scv * acc / den
  float* outp = fa.out + (size_t)(bb*2048 + qt*128 + w*32) * 512 + zcol;
#pragma unroll
  for (int r = 0; r < 16; ++r) {
    const int row = (r & 3) + 8*(r >> 2) + 4*lh;
    const float f = scv / den[r];
#pragma unroll
    for (int nt = 0; nt < 8; ++nt)
      unsafeAtomicAdd(&outp[(size_t)row*512 + nt*32 + l31], acc[nt][r] * f);
  }
}

// ---------------------------------------------------------------- launch
extern "C" void kernel_launch(void* const* d_in, const int* in_sizes, int n_in,
                              void* d_out, int out_size, void* d_ws, size_t ws_size,
                              hipStream_t stream) {
  (void)in_sizes; (void)n_in; (void)out_size; (void)ws_size;

  __bf16* wsp = (__bf16*)d_ws;
  const size_t XE = (size_t)16384 * 256;
  const size_t QK = (size_t)16384 * 32;
  const size_t VT = (size_t)8 * 256 * 2048;

  __bf16* xe = wsp;
  __bf16* xp = wsp + XE;
  __bf16* base = wsp + 2*XE;

  ProjArgs pa;
  pa.xe = xe; pa.xp = xp;
  const float* x = (const float*)d_in[0];
  const float* wsrc[12];
  for (int i = 0; i < 12; ++i) wsrc[i] = (const float*)d_in[1 + i];
  for (int i = 0; i < 4; ++i) pa.q[i]  = base + (size_t)i * QK;
  for (int i = 0; i < 4; ++i) pa.k[i]  = base + (size_t)(4 + i) * QK;
  for (int i = 0; i < 4; ++i) pa.vt[i] = base + 8*QK + (size_t)i * VT;
  __bf16* wt = base + 8*QK + 4*VT;
  pa.wt = wt;

  WcatArgs wa;
  wa.wt = wt;
  const int qk_w[4][2] = {{0, 3}, {1, 10}, {6, 9}, {4, 7}};
  const float qk_s[4] = {QSCALE, 1.0f, QSCALE, 1.0f};
  for (int g = 0; g < 4; ++g)
    for (int h = 0; h < 2; ++h) {
      const int e = g*2 + h;
      wa.src[e] = wsrc[qk_w[g][h]];
      wa.c0[e] = 0; wa.dout[e] = 32; wa.scale[e] = qk_s[g];
    }
  const int v_w[4] = {2, 11, 5, 8};
  for (int vi = 0; vi < 4; ++vi)
    for (int t = 0; t < 4; ++t)
      for (int h = 0; h < 2; ++h) {
        const int e = (4 + vi*4 + t)*2 + h;
        wa.src[e] = wsrc[v_w[vi]];
        wa.c0[e] = t*64 + h*32; wa.dout[e] = 256; wa.scale[e] = 1.0f;
      }

  hipMemsetAsync(d_out, 0, (size_t)8*2048*512*4, stream);
  hipLaunchKernelGGL(deint_kernel, dim3(2048), dim3(256), 0, stream, x, xe, xp);
  hipLaunchKernelGGL(wcat_kernel, dim3(1280), dim3(256), 0, stream, wa);
  hipLaunchKernelGGL(proj_kernel, dim3(20, 128), dim3(256), 0, stream, pa);

  FlashArgs fl;
  for (int i = 0; i < 4; ++i) { fl.q[i] = pa.q[i]; fl.k[i] = pa.k[i]; fl.v[i] = pa.vt[i]; }
  fl.alpha = (const float*)d_in[13];
  fl.gamma = (const float*)d_in[14];
  fl.out = (float*)d_out;
  hipLaunchKernelGGL(flash_kernel, dim3(512), dim3(256), 0, stream, fl);
}

// Round 9
// 291.597 us; speedup vs baseline: 1.3542x; 1.0073x over previous
//
#include <hip/hip_runtime.h>

// B=8, L=2048, C=256, D=32. Four attentions (ecg/pcg intra/inter),
// out = concat(inter + scalar*intra) -> (8,2048,512) f32.
//
// Pipeline:
//   1) hipMemsetAsync(d_out, 0); all four attentions atomically accumulate.
//   2) deint_kernel : x f32 interleaved -> xe, xp bf16 [16384][256]
//   3) wcat_kernel  : 12 f32 weights -> bf16 B^T WT[1280][256] (Q rows pre-scaled)
//   4) proj_kernel  : xe/xp @ WT -> Q[4],K[4], V in VF layout VF[b][k8][vcol][8keys]
//   5) flash_kernel : r8 structure + ONE-ITERATION SOFTWARE PIPELINE:
//      pf (S^T -> exp2 -> shfl) for kt+1 is built during kt; the PV burst runs at
//      the top of each iteration on the previous pf, so PV covers K-load latency
//      and the softmax tail covers the DMA staging (r8 was exposed-latency bound:
//      ~160 cyc/key serial vs ~28 cyc/key of pipe work).

typedef __bf16 v8bf __attribute__((ext_vector_type(8)));
typedef float  v16f __attribute__((ext_vector_type(16)));
typedef unsigned int u32;

typedef __attribute__((address_space(1))) const void gvoid;
typedef __attribute__((address_space(3))) void svoid;

#define QSCALE 0.25500526817276613f  // log2(e)/sqrt(32)

union frag_u { u32 d[4]; v8bf v; };
union pk_u { unsigned short s[2]; u32 d; };

static __device__ inline u32 pack_bf16(float x, float y) {
  pk_u u;
  __bf16 a = (__bf16)x, b = (__bf16)y;
  u.s[0] = *(unsigned short*)&a;
  u.s[1] = *(unsigned short*)&b;
  return u.d;
}

// ---------------------------------------------------------------- deinterleave
__global__ __launch_bounds__(256) void deint_kernel(const float* __restrict__ x,
                                                    __bf16* __restrict__ xe,
                                                    __bf16* __restrict__ xp) {
  const size_t i = (size_t)blockIdx.x * 256 + threadIdx.x;
  const float4* xin = (const float4*)(x + i * 16);
  float4 a = xin[0], b = xin[1], c = xin[2], d = xin[3];
  v8bf ev, pv;
  ev[0]=(__bf16)a.x; ev[1]=(__bf16)a.z; ev[2]=(__bf16)b.x; ev[3]=(__bf16)b.z;
  ev[4]=(__bf16)c.x; ev[5]=(__bf16)c.z; ev[6]=(__bf16)d.x; ev[7]=(__bf16)d.z;
  pv[0]=(__bf16)a.y; pv[1]=(__bf16)a.w; pv[2]=(__bf16)b.y; pv[3]=(__bf16)b.w;
  pv[4]=(__bf16)c.y; pv[5]=(__bf16)c.w; pv[6]=(__bf16)d.y; pv[7]=(__bf16)d.w;
  *(v8bf*)(xe + i * 8) = ev;
  *(v8bf*)(xp + i * 8) = pv;
}

// ---------------------------------------------------------------- weight pack
struct WcatArgs {
  const float* src[40];
  int c0[40];
  int dout[40];
  float scale[40];
  __bf16* wt;             // [1280][256]
};

__global__ __launch_bounds__(256) void wcat_kernel(WcatArgs wa) {
  const int r = blockIdx.x, e = r >> 5, k = threadIdx.x;
  const float v = wa.src[e][(size_t)k * wa.dout[e] + wa.c0[e] + (r & 31)] * wa.scale[e];
  wa.wt[(size_t)r * 256 + k] = (__bf16)v;
}

// ---------------------------------------------------------------- projections
struct ProjArgs {
  const __bf16* xe;
  const __bf16* xp;
  const __bf16* wt;
  __bf16* q[4];
  __bf16* k[4];
  __bf16* vt[4];   // VF layout: [b][k8][vcol][8 keys]
};

// grid (20 jobs, 128 row-tiles of 128), block 256 (4 waves x 32 rows, 64 cols).
__global__ __launch_bounds__(256) void proj_kernel(ProjArgs pa) {
  const int job = blockIdx.x;
  const int rb  = blockIdx.y * 128;
  const int tid = threadIdx.x;
  const int lane = tid & 63, w = tid >> 6;
  const int l31 = lane & 31, lh = lane >> 5;

  __shared__ __bf16 lds_B[64 * 264];     // rows 528B
  __shared__ __bf16 lds_A[2][128 * 72];  // dbuf BK=64, rows 144B

  int src, vcol0 = 0, vmode = 0;
  __bf16* dqk[2] = {nullptr, nullptr};
  __bf16* vdst = nullptr;
  if (job < 4) {
    switch (job) {
      case 0: src=0; dqk[0]=pa.q[0]; dqk[1]=pa.q[1]; break;
      case 1: src=0; dqk[0]=pa.k[0]; dqk[1]=pa.k[3]; break;
      case 2: src=1; dqk[0]=pa.q[2]; dqk[1]=pa.q[3]; break;
      default:src=1; dqk[0]=pa.k[1]; dqk[1]=pa.k[2]; break;
    }
  } else {
    const int vi = (job - 4) >> 2, t = (job - 4) & 3;
    const int vbuf = (vi==0) ? 0 : (vi==1) ? 3 : (vi==2) ? 1 : 2;
    vmode = 1; src = vi >> 1;
    vcol0 = t*64; vdst = pa.vt[vbuf];
  }

  const __bf16* X = src ? pa.xp : pa.xe;

  // B loads (once): WT rows job*64..+63
  int4 breg[8];
  int brow[8], bch[8];
#pragma unroll
  for (int i = 0; i < 8; ++i) {
    const int idx = tid + i*256;
    brow[i] = idx >> 5; bch[i] = idx & 31;
    breg[i] = *(const int4*)(pa.wt + ((size_t)(job*64 + brow[i])*256 + bch[i]*8));
  }
  int arow[4], ach[4];
#pragma unroll
  for (int i = 0; i < 4; ++i) {
    const int idx = tid + i*256;
    arow[i] = idx >> 3; ach[i] = idx & 7;
  }
  int4 areg[4];
#define LOAD_A(kb)                                                              \
  _Pragma("unroll")                                                             \
  for (int i = 0; i < 4; ++i)                                                   \
    areg[i] = *(const int4*)(X + ((size_t)(rb + arow[i])*256 + (kb)*64 + ach[i]*8));

#define WRITE_A(buf)                                                            \
  _Pragma("unroll")                                                             \
  for (int i = 0; i < 4; ++i)                                                   \
    *(int4*)&lds_A[buf][arow[i]*72 + ach[i]*8] = areg[i];

  LOAD_A(0)
#pragma unroll
  for (int i = 0; i < 8; ++i)
    *(int4*)&lds_B[brow[i]*264 + bch[i]*8] = breg[i];
  WRITE_A(0)
  LOAD_A(1)
  __syncthreads();

  v16f acc[2];
#pragma unroll
  for (int n = 0; n < 2; ++n)
#pragma unroll
    for (int i = 0; i < 16; ++i) acc[n][i] = 0.f;

  for (int kb = 0; kb < 4; ++kb) {
    if (kb < 3) WRITE_A((kb + 1) & 1)
    if (kb < 2) LOAD_A(kb + 2)
    const __bf16* ab = &lds_A[kb & 1][0];
#pragma unroll
    for (int kk = 0; kk < 4; ++kk) {
      const v8bf af = *(const v8bf*)&ab[(w*32 + l31)*72 + (kk*2 + lh)*8];
#pragma unroll
      for (int nt = 0; nt < 2; ++nt) {
        const v8bf bf = *(const v8bf*)&lds_B[(nt*32 + l31)*264 + kb*64 + kk*16 + lh*8];
        acc[nt] = __builtin_amdgcn_mfma_f32_32x32x16_bf16(af, bf, acc[nt], 0, 0, 0);
      }
    }
    __syncthreads();
  }

  if (!vmode) {
    // Q/K row-major [16384][32] (scale pre-folded into WT)
#pragma unroll
    for (int nt = 0; nt < 2; ++nt) {
      __bf16* dst = dqk[nt];
#pragma unroll
      for (int r = 0; r < 16; ++r) {
        const int row = rb + w*32 + (r & 3) + 8*(r >> 2) + 4*lh;
        dst[(size_t)row*32 + l31] = (__bf16)acc[nt][r];
      }
    }
  } else {
    // V: transpose 128keys x 64vcols tile through LDS, then write VF[b][k8][vcol]
    __bf16 (*lds_t)[136] = (__bf16 (*)[136])&lds_A[0][0];  // 64 x 272B rows
#pragma unroll
    for (int nt = 0; nt < 2; ++nt) {
#pragma unroll
      for (int r = 0; r < 16; ++r) {
        const int row = w*32 + (r & 3) + 8*(r >> 2) + 4*lh;
        lds_t[nt*32 + l31][row] = (__bf16)acc[nt][r];
      }
    }
    __syncthreads();
    const int bb = rb >> 11, k8base = (rb & 2047) >> 3;
    for (int i = tid; i < 1024; i += 256) {
      const int seg = i >> 6, vrow = i & 63;
      *(int4*)&vdst[(((size_t)bb*256 + k8base + seg)*256 + vcol0 + vrow)*8] =
          *(const int4*)&lds_t[vrow][seg*8];
    }
  }
}

// ---------------------------------------------------------------- flash attention
struct FlashArgs {
  const __bf16* q[4];
  const __bf16* k[4];
  const __bf16* v[4];   // VF layout
  const float* alpha;
  const float* gamma;
  float* out;
};

// 512 blocks x 256 thr. flat = pair + 32*qt (pair%8 pins (att,bb) to an XCD).
// Wave: 32 q x 256 vcols, 32 kt of 64 keys. One-iteration software pipeline:
// PV(kt) runs on pf built during kt-1; K(kt+1) loads + V DMA(kt+1) fly under PV.
__global__ __launch_bounds__(256, 2) void flash_kernel(FlashArgs fa) {
  const int flat = blockIdx.x;
  const int pair = flat & 31, qt = flat >> 5;
  const int att = pair & 3, bb = pair >> 2;
  const int tid = threadIdx.x;
  const int lane = tid & 63, w = tid >> 6;
  const int l31 = lane & 31, lh = lane >> 5;

  __shared__ __bf16 v_lds[2][16384];  // 2 x (8 k8 x 256 vcols x 8 keys)

  const __bf16* Q  = fa.q[att] + (size_t)bb*2048*32;
  const __bf16* Kb = fa.k[att] + (size_t)bb*2048*32;
  const __bf16* VF = fa.v[att] + (size_t)bb*256*2048;  // VF[b][k8][vcol][8]
  float scv = 1.0f;
  if (att == 0) scv = fa.alpha[0];
  if (att == 2) scv = fa.gamma[0];
  const int zcol = (att >> 1) * 256;

  // Q B-frags (resident): B[n=q=l31][k=d = c*16 + lh*8 + j]
  const int qrow = qt*128 + w*32 + l31;
  const v8bf qf0 = *(const v8bf*)&Q[(size_t)qrow*32 + lh*8];
  const v8bf qf1 = *(const v8bf*)&Q[(size_t)qrow*32 + 16 + lh*8];

#define STAGE_V(buf, kt)                                                        \
  {                                                                             \
    const size_t kb8 = (size_t)(kt) * 8;                                        \
    _Pragma("unroll")                                                           \
    for (int i = 0; i < 8; ++i) {                                               \
      const int c = w*8 + i, k8l = c >> 2, vq = c & 3;                          \
      __builtin_amdgcn_global_load_lds(                                         \
          (gvoid*)&VF[((kb8 + k8l)*256 + vq*64 + lane)*8],                      \
          (svoid*)&v_lds[buf][((size_t)(k8l*256 + vq*64 + lane))*8], 16, 0, 0); \
    }                                                                           \
  }

  // K A-frags: A[m=key = t*32+l31][k=d]
  v8bf kf[2][2];
#define LOAD_K(kb)                                                              \
  _Pragma("unroll")                                                             \
  for (int t = 0; t < 2; ++t)                                                   \
    _Pragma("unroll")                                                           \
    for (int c = 0; c < 2; ++c)                                                 \
      kf[t][c] = *(const v8bf*)&Kb[((size_t)((kb) + t*32 + l31))*32 + c*16 + lh*8];

  v8bf ones;
#pragma unroll
  for (int i = 0; i < 8; ++i) ones[i] = (__bf16)1.0f;

  v16f acc[8], den;
#pragma unroll
  for (int n = 0; n < 8; ++n)
#pragma unroll
    for (int i = 0; i < 16; ++i) acc[n][i] = 0.f;
#pragma unroll
  for (int i = 0; i < 16; ++i) den[i] = 0.f;

  v8bf pf[4];  // P A-frags, always built one iteration ahead

  // S^T -> exp2 -> lane-pair shfl -> pf (consumes kf; register-only)
  auto compute_pf = [&]() {
    v16f st0, st1;
#pragma unroll
    for (int i = 0; i < 16; ++i) { st0[i] = 0.f; st1[i] = 0.f; }
    st0 = __builtin_amdgcn_mfma_f32_32x32x16_bf16(kf[0][0], qf0, st0, 0, 0, 0);
    st0 = __builtin_amdgcn_mfma_f32_32x32x16_bf16(kf[0][1], qf1, st0, 0, 0, 0);
    st1 = __builtin_amdgcn_mfma_f32_32x32x16_bf16(kf[1][0], qf0, st1, 0, 0, 0);
    st1 = __builtin_amdgcn_mfma_f32_32x32x16_bf16(kf[1][1], qf1, st1, 0, 0, 0);

    u32 pk0[8], pk1[8];
#pragma unroll
    for (int i = 0; i < 8; ++i) {
      pk0[i] = pack_bf16(__builtin_exp2f(st0[2*i]), __builtin_exp2f(st0[2*i + 1]));
      pk1[i] = pack_bf16(__builtin_exp2f(st1[2*i]), __builtin_exp2f(st1[2*i + 1]));
    }
#pragma unroll
    for (int half = 0; half < 2; ++half) {
      const u32* pk = half ? pk1 : pk0;
#pragma unroll
      for (int f2 = 0; f2 < 2; ++f2) {
        const u32 keep0 = lh ? pk[f2*4 + 2] : pk[f2*4 + 0];
        const u32 keep1 = lh ? pk[f2*4 + 3] : pk[f2*4 + 1];
        const u32 send0 = lh ? pk[f2*4 + 0] : pk[f2*4 + 2];
        const u32 send1 = lh ? pk[f2*4 + 1] : pk[f2*4 + 3];
        const u32 recv0 = (u32)__shfl_xor((int)send0, 32, 64);
        const u32 recv1 = (u32)__shfl_xor((int)send1, 32, 64);
        frag_u fu;
        fu.d[0] = lh ? recv0 : keep0;
        fu.d[1] = lh ? recv1 : keep1;
        fu.d[2] = lh ? keep0 : recv0;
        fu.d[3] = lh ? keep1 : recv1;
        pf[half*2 + f2] = fu.v;
      }
    }
  };

  // prologue: stage V(0); build pf for kt=0
  STAGE_V(0, 0)
  LOAD_K(0)
  compute_pf();
  __syncthreads();

  for (int kt = 0; kt < 32; ++kt) {
    const int cur = kt & 1;
    // issue next tile's DMA + next K loads under the PV burst
    if (kt < 31) {
      STAGE_V(cur ^ 1, kt + 1)
      LOAD_K((kt + 1) * 64)
    }

    // PV burst with pf from the previous iteration (deps: LDS cur buffer only)
    const __bf16* vb = &v_lds[cur][0];
#pragma unroll
    for (int kc = 0; kc < 4; ++kc) {
      den = __builtin_amdgcn_mfma_f32_32x32x16_bf16(pf[kc], ones, den, 0, 0, 0);
      const __bf16* vrow = &vb[(size_t)((kc*2 + lh)*256)*8];
#pragma unroll
      for (int nt = 0; nt < 8; ++nt) {
        const v8bf vf = *(const v8bf*)&vrow[(size_t)(nt*32 + l31)*8];
        acc[nt] = __builtin_amdgcn_mfma_f32_32x32x16_bf16(pf[kc], vf, acc[nt], 0, 0, 0);
      }
    }

    // build pf for kt+1 (kf loaded above; overlaps the DMA in flight)
    if (kt < 31) compute_pf();
    __syncthreads();  // drains staging vmcnt + all waves done with cur buffer
  }

  // epilogue: atomic accumulate scv * acc / den
  float* outp = fa.out + (size_t)(bb*2048 + qt*128 + w*32) * 512 + zcol;
#pragma unroll
  for (int r = 0; r < 16; ++r) {
    const int row = (r & 3) + 8*(r >> 2) + 4*lh;
    const float f = scv / den[r];
#pragma unroll
    for (int nt = 0; nt < 8; ++nt)
      unsafeAtomicAdd(&outp[(size_t)row*512 + nt*32 + l31], acc[nt][r] * f);
  }
}

// ---------------------------------------------------------------- launch
extern "C" void kernel_launch(void* const* d_in, const int* in_sizes, int n_in,
                              void* d_out, int out_size, void* d_ws, size_t ws_size,
                              hipStream_t stream) {
  (void)in_sizes; (void)n_in; (void)out_size; (void)ws_size;

  __bf16* wsp = (__bf16*)d_ws;
  const size_t XE = (size_t)16384 * 256;
  const size_t QK = (size_t)16384 * 32;
  const size_t VT = (size_t)8 * 256 * 2048;

  __bf16* xe = wsp;
  __bf16* xp = wsp + XE;
  __bf16* base = wsp + 2*XE;

  ProjArgs pa;
  pa.xe = xe; pa.xp = xp;
  const float* x = (const float*)d_in[0];
  const float* wsrc[12];
  for (int i = 0; i < 12; ++i) wsrc[i] = (const float*)d_in[1 + i];
  for (int i = 0; i < 4; ++i) pa.q[i]  = base + (size_t)i * QK;
  for (int i = 0; i < 4; ++i) pa.k[i]  = base + (size_t)(4 + i) * QK;
  for (int i = 0; i < 4; ++i) pa.vt[i] = base + 8*QK + (size_t)i * VT;
  __bf16* wt = base + 8*QK + 4*VT;
  pa.wt = wt;

  WcatArgs wa;
  wa.wt = wt;
  const int qk_w[4][2] = {{0, 3}, {1, 10}, {6, 9}, {4, 7}};
  const float qk_s[4] = {QSCALE, 1.0f, QSCALE, 1.0f};
  for (int g = 0; g < 4; ++g)
    for (int h = 0; h < 2; ++h) {
      const int e = g*2 + h;
      wa.src[e] = wsrc[qk_w[g][h]];
      wa.c0[e] = 0; wa.dout[e] = 32; wa.scale[e] = qk_s[g];
    }
  const int v_w[4] = {2, 11, 5, 8};
  for (int vi = 0; vi < 4; ++vi)
    for (int t = 0; t < 4; ++t)
      for (int h = 0; h < 2; ++h) {
        const int e = (4 + vi*4 + t)*2 + h;
        wa.src[e] = wsrc[v_w[vi]];
        wa.c0[e] = t*64 + h*32; wa.dout[e] = 256; wa.scale[e] = 1.0f;
      }

  hipMemsetAsync(d_out, 0, (size_t)8*2048*512*4, stream);
  hipLaunchKernelGGL(deint_kernel, dim3(2048), dim3(256), 0, stream, x, xe, xp);
  hipLaunchKernelGGL(wcat_kernel, dim3(1280), dim3(256), 0, stream, wa);
  hipLaunchKernelGGL(proj_kernel, dim3(20, 128), dim3(256), 0, stream, pa);

  FlashArgs fl;
  for (int i = 0; i < 4; ++i) { fl.q[i] = pa.q[i]; fl.k[i] = pa.k[i]; fl.v[i] = pa.vt[i]; }
  fl.alpha = (const float*)d_in[13];
  fl.gamma = (const float*)d_in[14];
  fl.out = (float*)d_out;
  hipLaunchKernelGGL(flash_kernel, dim3(512), dim3(256), 0, stream, fl);
}